// Round 10
// baseline (437.317 us; speedup 1.0000x reference)
//
#include <hip/hip_runtime.h>
#include <hip/hip_bf16.h>
#include <math.h>

// ---------------------------------------------------------------------------
// Bidirectional Mamba (bimamba v2), B=2, L=2048, D_MODEL=1024, D_INNER=2048,
// D_STATE=16, DT_RANK=64, D_CONV=4.
//
//   K0  cvt   : inw/hid + dtw/dtw_b -> bf16 (2 paired launches)
//   K1  mfma  : x[d][n] + zt[n][d] = in_proj_w @ hidden^T   (async bf16 GEMM)
//   K2  conv  : xcf/xcb[n][d] = silu(causal dwconv(x)), LDS transpose
//   K3  gemm  : split-K=8 partials, both branches one launch + fused reduce
//   K4  mfma  : dlt[n][d] = softplus(dt_r^T @ dtw^T + bias)  (async bf16)
//   K5  scan  : 3-phase chunked scan, runtime nch (64 if ws extension fits).
//               Z-GATING FACTORED OUT (R10): both directions gate by
//               silu(z) at the SAME output token, so part3 now stores the
//               pre-gate value y+u*D and gatesum_k computes
//               (yf+yb)*silu(z). Removes part3's z stream (-67MB) and its
//               16-register z/index pipeline -> natural VGPR ~56-64, which
//               (if <=64) doubles the wave allowance to 8/SIMD; nch=64
//               supplies the matching 32 waves/CU. NO __launch_bounds__
//               forcing (R7/R8: forcing spills, twice confirmed).
//               Depth-2 u/delta register pipeline + exp2 pre-scaled A kept.
//   K5b cvt/gatesum: outw -> bf16; ygsum = (ygt_f+ygt_b)*silu(zt) (bf16)
//   K6  mfma  : out[n][m] = out_proj_w @ ygsum  (async bf16 GEMM, MT=64)
//
// gemm_bf16 / dtproj_mfma: 2-phase pipeline (T3+T4): double-buffered LDS,
// counted s_waitcnt vmcnt(N) (never 0 in main loop) + raw s_barrier.
//
// Workspace: base 55,967,744 floats = 213.5 MiB; +8,912,896 floats
// (nch=64 SS/HL extension) = 247.5 MiB when available.
// ---------------------------------------------------------------------------

#define L_SEQ  2048
#define B_SZ   2
#define DM     1024
#define DI     2048
#define NST    16
#define RTOT   96
#define DTR    64
#define NTOT   (B_SZ * L_SEQ)   // 4096
#define ETOT   (2 * DI)         // 4096
#define SPLK   8
#define CHTMAX 64

#define LOG2E  1.44269504088896340736f

// workspace offsets (in floats)
#define OFF_X    ((size_t)0)                        // [DI][NTOT] x; later DLTF [NTOT][DI]
#define OFF_ZT   (OFF_X   + (size_t)DI * NTOT)      // [NTOT][DI] z transposed
#define OFF_XCF  (OFF_ZT  + (size_t)DI * NTOT)      // [NTOT][DI] u fwd; later ygsum (bf16)
#define OFF_XCB  (OFF_XCF + (size_t)DI * NTOT)      // [NTOT][DI] u bwd; later outw bf16
#define OFF_DLTB (OFF_XCB + (size_t)DI * NTOT)      // [NTOT][DI] delta bwd
#define OFF_XDF  (OFF_DLTB + (size_t)DI * NTOT)     // [96][NTOT]
#define OFF_XDB  (OFF_XDF + (size_t)RTOT * NTOT)
#define OFF_SS   (OFF_XDB + (size_t)RTOT * NTOT)    // [4][32][DI]; pre-K1: inw/hid bf16
#define OFF_HL   (OFF_SS  + (size_t)4 * 32 * DI)    // [4][32][NST][DI]
#define OFF_YGTF (OFF_HL  + (size_t)4 * 32 * NST * DI)    // bf16 [NTOT][DI]; K3 scratch
#define OFF_YGTB (OFF_YGTF + (size_t)NTOT * DI / 2)
#define OFF_XDT16F (OFF_YGTB + (size_t)NTOT * DI / 2)     // bf16 [NTOT][DTR]
#define OFF_XDT16B (OFF_XDT16F + (size_t)NTOT * DTR / 2)
#define OFF_DTW16F (OFF_XDT16B + (size_t)NTOT * DTR / 2)  // bf16 [DI][DTR]
#define OFF_DTW16B (OFF_DTW16F + (size_t)DI * DTR / 2)
#define WS_FLOATS  (OFF_DTW16B + (size_t)DI * DTR / 2)    // 55,967,744
// nch=64 extension: SS64 [4][64][DI] + HL64 [4][64][NST][DI]
#define WS64_FLOATS (WS_FLOATS + (size_t)4 * 64 * DI + (size_t)4 * 64 * NST * DI)

typedef __bf16 bf16x8 __attribute__((ext_vector_type(8)));
typedef float  floatx4 __attribute__((ext_vector_type(4)));

__device__ __forceinline__ float silu_f(float x) {
    return x / (1.f + __expf(-x));
}

// async global(16B/lane) -> LDS; dest = wave-uniform base + lane*16
__device__ __forceinline__ void gl2lds16(const __bf16* g, __bf16* l) {
    __builtin_amdgcn_global_load_lds(
        (const __attribute__((address_space(1))) unsigned int*)g,
        (__attribute__((address_space(3))) unsigned int*)l, 16, 0, 0);
}

// ---------------------------------------------------------------------------
// Async bf16 MFMA GEMM: C[M][N] (fp32) = A[M][K] @ B[N][K]^T, MT x 128 tile,
// 4 waves (2x2), BK=32. LDS rows are 32 bf16 (64 B), XOR-swizzled blocks.
// 2-phase pipeline: double-buffered LDS, counted vmcnt, raw barriers.
// TRANS: C stored [N][M]. SPLITZ: gm<DI -> C[d][n]; gm>=DI -> C2[n][gm-DI].
// ---------------------------------------------------------------------------
template<int MT, bool TRANS, bool SPLITZ>
__global__ __launch_bounds__(256)
void gemm_bf16(const __bf16* __restrict__ A, const __bf16* __restrict__ B,
               float* __restrict__ C, float* __restrict__ C2,
               int M, int N, int K)
{
    static_assert(MT == 64 || MT == 128, "vmcnt literals assume MT in {64,128}");
    __shared__ __attribute__((aligned(16))) __bf16 As[2][MT * 32];
    __shared__ __attribute__((aligned(16))) __bf16 Bs[2][128 * 32];
    const int tid  = threadIdx.x;
    const int m0   = blockIdx.y * MT;
    const int n0   = blockIdx.x * 128;
    const int lane = tid & 63;
    const int wave = tid >> 6;
    const int wy   = wave >> 1, wx = wave & 1;
    const int lr   = lane & 15;
    const int q    = lane >> 4;
    constexpr int MF = MT / 32;

    floatx4 acc[MF][4];
#pragma unroll
    for (int i = 0; i < MF; ++i)
#pragma unroll
        for (int j = 0; j < 4; ++j) acc[i][j] = (floatx4)(0.0f);

    const int rl = lane >> 2;
    const int cp = lane & 3;
    const int sw = (q ^ ((lr >> 2) & 3)) * 8;

    auto stage = [&](int s, int k0) {
#pragma unroll
        for (int is = 0; is < MT / 64; ++is) {
            int r0  = wave * (MT / 4) + is * 16;
            int row = r0 + rl;
            int c   = cp ^ ((row >> 2) & 3);
            gl2lds16(A + (size_t)(m0 + row) * K + k0 + c * 8, &As[s][r0 * 32]);
        }
#pragma unroll
        for (int is = 0; is < 2; ++is) {
            int r0  = wave * 32 + is * 16;
            int row = r0 + rl;
            int c   = cp ^ ((row >> 2) & 3);
            gl2lds16(B + (size_t)(n0 + row) * K + k0 + c * 8, &Bs[s][r0 * 32]);
        }
    };

    stage(0, 0);                     // prologue: tile 0 in flight
    int cur = 0;
    for (int k0 = 0; k0 < K; k0 += 32) {
        if (k0 + 32 < K) {
            stage(cur ^ 1, k0 + 32); // issue next tile BEFORE computing current
            if constexpr (MT == 128) {
                asm volatile("s_waitcnt vmcnt(4)" ::: "memory");  // cur tile landed
            } else {
                asm volatile("s_waitcnt vmcnt(3)" ::: "memory");
            }
        } else {
            asm volatile("s_waitcnt vmcnt(0)" ::: "memory");      // last tile
        }
        __builtin_amdgcn_s_barrier();   // all waves' cur-tile DMA visible

        bf16x8 af[MF], bfr[4];
#pragma unroll
        for (int i = 0; i < MF; ++i)
            af[i] = *(const bf16x8*)&As[cur][(wy * (MT / 2) + i * 16 + lr) * 32 + sw];
#pragma unroll
        for (int j = 0; j < 4; ++j)
            bfr[j] = *(const bf16x8*)&Bs[cur][(wx * 64 + j * 16 + lr) * 32 + sw];
#pragma unroll
        for (int i = 0; i < MF; ++i)
#pragma unroll
            for (int j = 0; j < 4; ++j)
                acc[i][j] = __builtin_amdgcn_mfma_f32_16x16x32_bf16(
                    af[i], bfr[j], acc[i][j], 0, 0, 0);
        __builtin_amdgcn_s_barrier();   // reads of buf[cur] done -> next iter
        cur ^= 1;                       // may overwrite it
    }

    const int mb = m0 + wy * (MT / 2);
    const int nb = n0 + wx * 64;
#pragma unroll
    for (int i = 0; i < MF; ++i) {
#pragma unroll
        for (int j = 0; j < 4; ++j) {
            int gn  = nb + j * 16 + lr;
            int gm0 = mb + i * 16 + q * 4;     // rows gm0..gm0+3 <- acc[i][j][0..3]
            if constexpr (SPLITZ) {
                if (m0 < DI) {
#pragma unroll
                    for (int r = 0; r < 4; ++r)
                        C[(size_t)(gm0 + r) * N + gn] = acc[i][j][r];
                } else {
                    *(floatx4*)&C2[(size_t)gn * DI + (gm0 - DI)] = acc[i][j];
                }
            } else if constexpr (TRANS) {
                *(floatx4*)&C[(size_t)gn * M + gm0] = acc[i][j];
            } else {
#pragma unroll
                for (int r = 0; r < 4; ++r)
                    C[(size_t)(gm0 + r) * N + gn] = acc[i][j][r];
            }
        }
    }
}

// ---------------------------------------------------------------------------
// K4: dlt[n][d] = softplus(dt_r^T[n][r] @ dtw[d][r]^T + bias[d]).
// Async bf16 MFMA, M=NTOT, N=DI, K=DTR=64 (2 tiles, both issued up front),
// 128x128 tile, both branches via blockIdx.z. Coalesced [n][d] stores.
// ---------------------------------------------------------------------------
__global__ __launch_bounds__(256)
void dtproj_mfma(const __bf16* __restrict__ Af, const __bf16* __restrict__ Ab,
                 const __bf16* __restrict__ Bwf, const __bf16* __restrict__ Bwb,
                 const float* __restrict__ bif, const float* __restrict__ bib,
                 float* __restrict__ outf, float* __restrict__ outb)
{
    __shared__ __attribute__((aligned(16))) __bf16 As[2][128 * 32];
    __shared__ __attribute__((aligned(16))) __bf16 Bs[2][128 * 32];
    const int br = blockIdx.z;
    const __bf16* A  = br ? Ab : Af;     // [NTOT][DTR]
    const __bf16* B  = br ? Bwb : Bwf;   // [DI][DTR]
    const float*  bi = br ? bib : bif;
    float*        C  = br ? outb : outf; // [NTOT][DI]

    const int tid  = threadIdx.x;
    const int m0   = blockIdx.y * 128;   // n dim
    const int n0   = blockIdx.x * 128;   // d dim
    const int lane = tid & 63;
    const int wave = tid >> 6;
    const int wy   = wave >> 1, wx = wave & 1;
    const int lr   = lane & 15;
    const int q    = lane >> 4;

    floatx4 acc[4][4];
#pragma unroll
    for (int i = 0; i < 4; ++i)
#pragma unroll
        for (int j = 0; j < 4; ++j) acc[i][j] = (floatx4)(0.0f);

    const int rl = lane >> 2;
    const int cp = lane & 3;
    const int sw = (q ^ ((lr >> 2) & 3)) * 8;

    // issue both k-tiles (per wave: 2x(A+B) = 4 loads per tile, 8 total)
#pragma unroll
    for (int t = 0; t < 2; ++t) {
        int k0 = t * 32;
#pragma unroll
        for (int is = 0; is < 2; ++is) {
            int r0  = wave * 32 + is * 16;
            int row = r0 + rl;
            int c   = cp ^ ((row >> 2) & 3);
            gl2lds16(A + (size_t)(m0 + row) * DTR + k0 + c * 8, &As[t][r0 * 32]);
            gl2lds16(B + (size_t)(n0 + row) * DTR + k0 + c * 8, &Bs[t][r0 * 32]);
        }
    }

#pragma unroll
    for (int t = 0; t < 2; ++t) {
        if (t == 0) asm volatile("s_waitcnt vmcnt(4)" ::: "memory");
        else        asm volatile("s_waitcnt vmcnt(0)" ::: "memory");
        __builtin_amdgcn_s_barrier();

        bf16x8 af[4], bfr[4];
#pragma unroll
        for (int i = 0; i < 4; ++i)
            af[i] = *(const bf16x8*)&As[t][(wy * 64 + i * 16 + lr) * 32 + sw];
#pragma unroll
        for (int j = 0; j < 4; ++j)
            bfr[j] = *(const bf16x8*)&Bs[t][(wx * 64 + j * 16 + lr) * 32 + sw];
#pragma unroll
        for (int i = 0; i < 4; ++i)
#pragma unroll
            for (int j = 0; j < 4; ++j)
                acc[i][j] = __builtin_amdgcn_mfma_f32_16x16x32_bf16(
                    af[i], bfr[j], acc[i][j], 0, 0, 0);
    }

    const int mb = m0 + wy * 64;
    const int nb = n0 + wx * 64;
    float bj[4];
#pragma unroll
    for (int j = 0; j < 4; ++j) bj[j] = bi[nb + j * 16 + lr];
#pragma unroll
    for (int i = 0; i < 4; ++i) {
#pragma unroll
        for (int r = 0; r < 4; ++r) {
            int gm = mb + i * 16 + q * 4 + r;
#pragma unroll
            for (int j = 0; j < 4; ++j) {
                int gn = nb + j * 16 + lr;
                float x = acc[i][j][r] + bj[j];
                float o = (x > 20.f) ? x : __logf(1.f + __expf(x));
                C[(size_t)gm * DI + gn] = o;
            }
        }
    }
}

// ---------------------------------------------------------------------------
// cvt fp32 -> bf16, 8 elems/thread; paired launch (blockIdx.y selects set).
// ---------------------------------------------------------------------------
__global__ __launch_bounds__(256)
void cvt2_bf16_k(const float* __restrict__ ia, __bf16* __restrict__ oa,
                 const float* __restrict__ ib, __bf16* __restrict__ ob)
{
    const float* in  = blockIdx.y ? ib : ia;
    __bf16*      out = blockIdx.y ? ob : oa;
    const size_t i = ((size_t)blockIdx.x * 256 + threadIdx.x) * 8;
    float4 a = *(const float4*)(in + i);
    float4 b = *(const float4*)(in + i + 4);
    bf16x8 p;
    p[0]=(__bf16)a.x; p[1]=(__bf16)a.y; p[2]=(__bf16)a.z; p[3]=(__bf16)a.w;
    p[4]=(__bf16)b.x; p[5]=(__bf16)b.y; p[6]=(__bf16)b.z; p[7]=(__bf16)b.w;
    *(bf16x8*)(out + i) = p;
}

__global__ __launch_bounds__(256)
void cvt_bf16_k(const float* __restrict__ in, __bf16* __restrict__ out)
{
    const size_t i = ((size_t)blockIdx.x * 256 + threadIdx.x) * 8;
    float4 a = *(const float4*)(in + i);
    float4 b = *(const float4*)(in + i + 4);
    bf16x8 p;
    p[0]=(__bf16)a.x; p[1]=(__bf16)a.y; p[2]=(__bf16)a.z; p[3]=(__bf16)a.w;
    p[4]=(__bf16)b.x; p[5]=(__bf16)b.y; p[6]=(__bf16)b.z; p[7]=(__bf16)b.w;
    *(bf16x8*)(out + i) = p;
}

// ---------------------------------------------------------------------------
// gatesum_k: o[i] = bf16( ((float)a[i] + (float)b[i]) * silu(z[i]) ).
// The z-gating factored out of scan_part3 (both directions share silu(z)
// at the same output token).
// ---------------------------------------------------------------------------
__global__ __launch_bounds__(256)
void gatesum_k(const __bf16* __restrict__ a, const __bf16* __restrict__ b,
               const float* __restrict__ z, __bf16* __restrict__ o)
{
    const size_t i = ((size_t)blockIdx.x * 256 + threadIdx.x) * 8;
    bf16x8 x = *(const bf16x8*)(a + i);
    bf16x8 y = *(const bf16x8*)(b + i);
    float4 z0 = *(const float4*)(z + i);
    float4 z1 = *(const float4*)(z + i + 4);
    float zz[8] = { z0.x, z0.y, z0.z, z0.w, z1.x, z1.y, z1.z, z1.w };
    bf16x8 s;
#pragma unroll
    for (int e = 0; e < 8; ++e)
        s[e] = (__bf16)(((float)x[e] + (float)y[e]) * silu_f(zz[e]));
    *(bf16x8*)(o + i) = s;
}

// ---------------------------------------------------------------------------
// fp32 SIMT GEMM 128x128, KT=16 (K3 split-K). B is [N][K] (k contiguous).
// BOTH branches in one launch: blockIdx.z in [0,2*SPLK); z>=SPLK = backward.
// ---------------------------------------------------------------------------
__global__ __launch_bounds__(256)
void gemm_k3(const float* __restrict__ Af, const float* __restrict__ Bmf,
             float* __restrict__ Cf,
             const float* __restrict__ Ab, const float* __restrict__ Bmb,
             float* __restrict__ Cb,
             int M, int N, int K)
{
    __shared__ float As[16][132];
    __shared__ float Bs[16][132];
    const int tid = threadIdx.x;
    const int n0 = blockIdx.x * 128;
    const int m0 = blockIdx.y * 128;
    const int zz = blockIdx.z;
    const int brc = (zz >= SPLK) ? 1 : 0;
    const int kz  = zz & (SPLK - 1);
    const float* A  = brc ? Ab : Af;
    const float* Bm = brc ? Bmb : Bmf;
    float* C = (brc ? Cb : Cf) + (size_t)kz * M * N;
    int ksz  = K / SPLK;
    int kbeg = kz * ksz;
    int kend = kbeg + ksz;
    const int tx = tid & 15, ty = tid >> 4;

    float acc[8][8];
#pragma unroll
    for (int i = 0; i < 8; ++i)
#pragma unroll
        for (int j = 0; j < 8; ++j) acc[i][j] = 0.f;

    for (int k0 = kbeg; k0 < kend; k0 += 16) {
#pragma unroll
        for (int it = 0; it < 2; ++it) {
            int i = tid + it * 256;
            int m = i >> 2, kq = i & 3;
            float4 v = make_float4(0.f, 0.f, 0.f, 0.f);
            int gm = m0 + m;
            if (gm < M) v = *(const float4*)(A + (size_t)gm * K + (k0 + kq * 4));
            As[kq * 4 + 0][m] = v.x; As[kq * 4 + 1][m] = v.y;
            As[kq * 4 + 2][m] = v.z; As[kq * 4 + 3][m] = v.w;
        }
#pragma unroll
        for (int it = 0; it < 2; ++it) {
            int i = tid + it * 256;
            int n = i >> 2, kq = i & 3;
            float4 v = *(const float4*)(Bm + (size_t)(n0 + n) * K + (k0 + kq * 4));
            Bs[kq * 4 + 0][n] = v.x; Bs[kq * 4 + 1][n] = v.y;
            Bs[kq * 4 + 2][n] = v.z; Bs[kq * 4 + 3][n] = v.w;
        }
        __syncthreads();
#pragma unroll
        for (int kk = 0; kk < 16; ++kk) {
            float av[8], bv[8];
            *(float4*)&av[0] = *(const float4*)&As[kk][ty * 8];
            *(float4*)&av[4] = *(const float4*)&As[kk][ty * 8 + 4];
            *(float4*)&bv[0] = *(const float4*)&Bs[kk][tx * 8];
            *(float4*)&bv[4] = *(const float4*)&Bs[kk][tx * 8 + 4];
#pragma unroll
            for (int i = 0; i < 8; ++i)
#pragma unroll
                for (int j = 0; j < 8; ++j)
                    acc[i][j] = fmaf(av[i], bv[j], acc[i][j]);
        }
        __syncthreads();
    }

#pragma unroll
    for (int i = 0; i < 8; ++i) {
        int gm = m0 + ty * 8 + i;
        if (gm < M) {
            float* cp = C + (size_t)gm * N + n0 + tx * 8;
            *(float4*)cp       = make_float4(acc[i][0], acc[i][1], acc[i][2], acc[i][3]);
            *(float4*)(cp + 4) = make_float4(acc[i][4], acc[i][5], acc[i][6], acc[i][7]);
        }
    }
}

// ---------------------------------------------------------------------------
// reduce8t_k: out[i] = sum_z P[z*stride+i]; rows r<DTR also emit bf16
// transposed copy out2[n][r]. BOTH branches in one launch (blockIdx.y).
// ---------------------------------------------------------------------------
__global__ __launch_bounds__(256)
void reduce8t_k(const float* __restrict__ Pf, float* __restrict__ outf,
                __bf16* __restrict__ out2f,
                const float* __restrict__ Pb, float* __restrict__ outb,
                __bf16* __restrict__ out2b, size_t stride)
{
    const float* P   = blockIdx.y ? Pb : Pf;
    float*      outp = blockIdx.y ? outb : outf;
    __bf16*     out2 = blockIdx.y ? out2b : out2f;
    const size_t i4 = ((size_t)blockIdx.x * 256 + threadIdx.x) * 4;
    float4 s = *(const float4*)(P + i4);
#pragma unroll
    for (int z = 1; z < SPLK; ++z) {
        float4 v = *(const float4*)(P + (size_t)z * stride + i4);
        s.x += v.x; s.y += v.y; s.z += v.z; s.w += v.w;
    }
    *(float4*)(outp + i4) = s;
    const int r = (int)(i4 >> 12);          // / NTOT
    if (r < DTR) {
        const int n = (int)(i4 & (NTOT - 1));
        out2[(size_t)(n + 0) * DTR + r] = (__bf16)s.x;
        out2[(size_t)(n + 1) * DTR + r] = (__bf16)s.y;
        out2[(size_t)(n + 2) * DTR + r] = (__bf16)s.z;
        out2[(size_t)(n + 3) * DTR + r] = (__bf16)s.w;
    }
}

// ---------------------------------------------------------------------------
// Causal depthwise conv (K=4) + silu, both directions; x [d][n] -> [n][d].
// ---------------------------------------------------------------------------
__global__ __launch_bounds__(256)
void conv_k(const float* __restrict__ x,
            const float* __restrict__ wf, const float* __restrict__ bf,
            const float* __restrict__ wb, const float* __restrict__ bb,
            float* __restrict__ xcf, float* __restrict__ xcb)
{
    __shared__ float xs[70 * 65];
    const int tid = threadIdx.x;
    const int d0 = blockIdx.x * 64;
    const int n0 = blockIdx.y * 64;
    const int b  = n0 >> 11;
    const int l0 = n0 & (L_SEQ - 1);
    const size_t bbase = (size_t)b << 11;

    for (int i = tid; i < 64 * 70; i += 256) {
        int r = i / 70, c = i % 70;
        int l = l0 - 3 + c;
        float v = 0.f;
        if (l >= 0 && l < L_SEQ) v = x[(size_t)(d0 + r) * NTOT + bbase + l];
        xs[c * 65 + r] = v;
    }
    __syncthreads();

    const int dd = tid & 63;
    const int lq = tid >> 6;
    const int d  = d0 + dd;
    const float w0 = wf[d * 4 + 0], w1 = wf[d * 4 + 1];
    const float w2 = wf[d * 4 + 2], w3 = wf[d * 4 + 3];
    const float v0 = wb[d * 4 + 0], v1 = wb[d * 4 + 1];
    const float v2 = wb[d * 4 + 2], v3 = wb[d * 4 + 3];
    const float bfv = bf[d], bbv = bb[d];

    for (int lr = 0; lr < 64; lr += 4) {
        const int lo = lr + lq;
        const int l  = l0 + lo;
        float x0 = xs[(lo + 0) * 65 + dd];
        float x1 = xs[(lo + 1) * 65 + dd];
        float x2 = xs[(lo + 2) * 65 + dd];
        float x3 = xs[(lo + 3) * 65 + dd];
        float x4 = xs[(lo + 4) * 65 + dd];
        float x5 = xs[(lo + 5) * 65 + dd];
        float x6 = xs[(lo + 6) * 65 + dd];
        float xf = bfv + w0 * x0 + w1 * x1 + w2 * x2 + w3 * x3;
        xcf[((size_t)bbase + l) * DI + d] = silu_f(xf);
        float xb = bbv + v3 * x3 + v2 * x4 + v1 * x5 + v0 * x6;
        xcb[((size_t)bbase + (L_SEQ - 1 - l)) * DI + d] = silu_f(xb);
    }
}

// ---------------------------------------------------------------------------
// Chunked scan phase 1 (runtime nch). B rows staged in LDS (broadcast);
// u/delta DEPTH-2 register pipeline; exp2 pre-scaled A rows. No forcing.
// ---------------------------------------------------------------------------
__global__ __launch_bounds__(256)
void scan_part1(const float* __restrict__ xcf, const float* __restrict__ xcb,
                const float* __restrict__ xdf, const float* __restrict__ xdb,
                const float* __restrict__ dltf, const float* __restrict__ dltb,
                const float* __restrict__ Alog_f, const float* __restrict__ Alog_b,
                float* __restrict__ SS, float* __restrict__ HL,
                int nch, int csh)
{
    __shared__ float Bsh[NST][CHTMAX];
    const int cht = 1 << csh;
    const int tid = threadIdx.x;
    const int d  = blockIdx.x * 256 + tid;
    const int c  = blockIdx.y;
    const int bb = blockIdx.z;
    const int b  = bb & 1;
    const int br = bb >> 1;

    const float* u    = br ? xcb : xcf;
    const float* dl   = br ? dltb : dltf;
    const float* xd   = br ? xdb : xdf;
    const float* Alog = br ? Alog_b : Alog_f;

    const size_t nbase = (size_t)b * L_SEQ + (size_t)c * cht;
    const float* bcB = xd + (size_t)DTR * NTOT + nbase;

    // stage B[n][t] into LDS, coalesced over t
    for (int i = tid; i < NST * cht; i += 256) {
        int n = i >> csh;
        int t = i & (cht - 1);
        Bsh[n][t] = bcB[(size_t)n * NTOT + t];
    }

    float Arow[NST], h[NST];
#pragma unroll
    for (int n = 0; n < NST; ++n) {
        Arow[n] = -__expf(Alog[d * NST + n]) * LOG2E;   // pre-scaled for exp2
        h[n] = 0.f;
    }
    float S = 0.f;

    const float* up = u  + nbase * DI + d;
    const float* dp = dl + nbase * DI + d;

    __syncthreads();

    // depth-2 pipeline: preload groups 0 and 1
    float dva[4], uva[4], dvb[4], uvb[4];
#pragma unroll
    for (int k = 0; k < 4; ++k) {
        dva[k] = dp[(size_t)k * DI];
        uva[k] = up[(size_t)k * DI];
    }
#pragma unroll
    for (int k = 0; k < 4; ++k) {
        dvb[k] = dp[(size_t)(4 + k) * DI];
        uvb[k] = up[(size_t)(4 + k) * DI];
    }

    for (int tr = 0; tr < cht; tr += 4) {
        // prefetch group tr+8 (over-reads land in adjacent live workspace
        // regions — in-bounds, values unused)
        float dvn[4], uvn[4];
#pragma unroll
        for (int k = 0; k < 4; ++k) {
            dvn[k] = dp[(size_t)(tr + 8 + k) * DI];
            uvn[k] = up[(size_t)(tr + 8 + k) * DI];
        }
        S += (dva[0] + dva[1]) + (dva[2] + dva[3]);
        float du[4] = { dva[0]*uva[0], dva[1]*uva[1], dva[2]*uva[2], dva[3]*uva[3] };
#pragma unroll
        for (int n = 0; n < NST; ++n) {
            float4 Bn = *(const float4*)&Bsh[n][tr];
            float hn = h[n];
            float An = Arow[n];
            hn = hn * __builtin_amdgcn_exp2f(dva[0] * An) + du[0] * Bn.x;
            hn = hn * __builtin_amdgcn_exp2f(dva[1] * An) + du[1] * Bn.y;
            hn = hn * __builtin_amdgcn_exp2f(dva[2] * An) + du[2] * Bn.z;
            hn = hn * __builtin_amdgcn_exp2f(dva[3] * An) + du[3] * Bn.w;
            h[n] = hn;
        }
#pragma unroll
        for (int k = 0; k < 4; ++k) {
            dva[k] = dvb[k]; uva[k] = uvb[k];
            dvb[k] = dvn[k]; uvb[k] = uvn[k];
        }
    }
    SS[((size_t)bb * nch + c) * DI + d] = S;
#pragma unroll
    for (int n = 0; n < NST; ++n)
        HL[(((size_t)bb * nch + c) * NST + n) * DI + d] = h[n];
}

__global__ __launch_bounds__(256)
void scan_part2(const float* __restrict__ SS, float* HL,
                const float* __restrict__ Alog_f, const float* __restrict__ Alog_b,
                int nch)
{
    const int d  = blockIdx.x * 256 + threadIdx.x;
    const int n  = blockIdx.y;
    const int bb = blockIdx.z;
    const int br = bb >> 1;
    const float* Alog = br ? Alog_b : Alog_f;
    const float A = -__expf(Alog[d * NST + n]) * LOG2E;

    float H = 0.f;
    for (int c = 0; c < nch; ++c) {
        const size_t si = ((size_t)bb * nch + c) * DI + d;
        const size_t hi = (((size_t)bb * nch + c) * NST + n) * DI + d;
        float hl = HL[hi];
        HL[hi] = H;
        H = __builtin_amdgcn_exp2f(SS[si] * A) * H + hl;
    }
}

// ---------------------------------------------------------------------------
// Chunked scan phase 3 (runtime nch). Z-GATING REMOVED (done in gatesum_k):
// stores pre-gate bf16(y + u*D). No z stream, no z/index register pipeline
// -> natural VGPR ~56-64 (no __launch_bounds__ forcing). B/C staged in LDS;
// u/delta DEPTH-2 register pipeline; exp2 pre-scaled A rows.
// ---------------------------------------------------------------------------
__global__ __launch_bounds__(256)
void scan_part3(const float* __restrict__ xcf, const float* __restrict__ xcb,
                const float* __restrict__ xdf, const float* __restrict__ xdb,
                const float* __restrict__ dltf, const float* __restrict__ dltb,
                const float* __restrict__ HIN,
                __bf16* __restrict__ ygtf, __bf16* __restrict__ ygtb,
                const float* __restrict__ Alog_f, const float* __restrict__ Alog_b,
                const float* __restrict__ Df, const float* __restrict__ Db,
                int nch, int csh)
{
    __shared__ float BCs[2 * NST][CHTMAX];   // rows 0..15 = B, 16..31 = C
    const int cht = 1 << csh;
    const int tid = threadIdx.x;
    const int d  = blockIdx.x * 256 + tid;
    const int c  = blockIdx.y;
    const int bb = blockIdx.z;
    const int b  = bb & 1;
    const int br = bb >> 1;

    const float* u    = br ? xcb : xcf;
    const float* dl   = br ? dltb : dltf;
    const float* xd   = br ? xdb : xdf;
    const float* Alog = br ? Alog_b : Alog_f;
    const float* Dv   = br ? Db : Df;
    __bf16*      ygt  = br ? ygtb : ygtf;

    const size_t nbase = (size_t)b * L_SEQ + (size_t)c * cht;
    const float* bcB = xd + (size_t)DTR * NTOT + nbase;

    // stage B and C; rows DTR.. are contiguous in xd
    for (int i = tid; i < 2 * NST * cht; i += 256) {
        int n = i >> csh;
        int t = i & (cht - 1);
        BCs[n][t] = bcB[(size_t)n * NTOT + t];
    }

    float Arow[NST], h[NST];
#pragma unroll
    for (int n = 0; n < NST; ++n) {
        Arow[n] = -__expf(Alog[d * NST + n]) * LOG2E;   // pre-scaled for exp2
        h[n] = HIN[(((size_t)bb * nch + c) * NST + n) * DI + d];
    }
    const float Dp = Dv[d];

    const float* up = u  + nbase * DI + d;
    const float* dp = dl + nbase * DI + d;
    const int    bL = b * L_SEQ;
    const int    t0 = c * cht;

    __syncthreads();

    // depth-2 pipeline for u/delta
    float dva[4], uva[4], dvb[4], uvb[4];
#pragma unroll
    for (int k = 0; k < 4; ++k) {
        dva[k] = dp[(size_t)k * DI];
        uva[k] = up[(size_t)k * DI];
    }
#pragma unroll
    for (int k = 0; k < 4; ++k) {
        dvb[k] = dp[(size_t)(4 + k) * DI];
        uvb[k] = up[(size_t)(4 + k) * DI];
    }

    for (int tr = 0; tr < cht; tr += 4) {
        // prefetch u/delta group tr+8 (over-reads land in adjacent live
        // workspace regions — in-bounds, values unused)
        float dvn[4], uvn[4];
#pragma unroll
        for (int k = 0; k < 4; ++k) {
            dvn[k] = dp[(size_t)(tr + 8 + k) * DI];
            uvn[k] = up[(size_t)(tr + 8 + k) * DI];
        }

        float du[4] = { dva[0]*uva[0], dva[1]*uva[1], dva[2]*uva[2], dva[3]*uva[3] };
        float y[4] = { 0.f, 0.f, 0.f, 0.f };
#pragma unroll
        for (int n = 0; n < NST; ++n) {
            float4 Bn = *(const float4*)&BCs[n][tr];
            float4 Cn = *(const float4*)&BCs[NST + n][tr];
            float hn = h[n];
            float An = Arow[n];
            hn = hn * __builtin_amdgcn_exp2f(dva[0] * An) + du[0] * Bn.x;  y[0] = fmaf(hn, Cn.x, y[0]);
            hn = hn * __builtin_amdgcn_exp2f(dva[1] * An) + du[1] * Bn.y;  y[1] = fmaf(hn, Cn.y, y[1]);
            hn = hn * __builtin_amdgcn_exp2f(dva[2] * An) + du[2] * Bn.z;  y[2] = fmaf(hn, Cn.z, y[2]);
            hn = hn * __builtin_amdgcn_exp2f(dva[3] * An) + du[3] * Bn.w;  y[3] = fmaf(hn, Cn.w, y[3]);
            h[n] = hn;
        }
#pragma unroll
        for (int k = 0; k < 4; ++k) {
            int t = t0 + tr + k;
            int nn = br ? (bL + (L_SEQ - 1 - t)) : (bL + t);
            ygt[(size_t)nn * DI + d] = (__bf16)(y[k] + uva[k] * Dp);
        }
#pragma unroll
        for (int k = 0; k < 4; ++k) {
            dva[k] = dvb[k]; uva[k] = uvb[k];
            dvb[k] = dvn[k]; uvb[k] = uvn[k];
        }
    }
}

extern "C" void kernel_launch(void* const* d_in, const int* in_sizes, int n_in,
                              void* d_out, int out_size, void* d_ws, size_t ws_size,
                              hipStream_t stream)
{
    const float* hid     = (const float*)d_in[0];
    const float* inw     = (const float*)d_in[1];
    const float* convw   = (const float*)d_in[2];
    const float* convb   = (const float*)d_in[3];
    const float* xpw     = (const float*)d_in[4];
    const float* dtw     = (const float*)d_in[5];
    const float* dtb     = (const float*)d_in[6];
    const float* Alog    = (const float*)d_in[7];
    const float* Dv      = (const float*)d_in[8];
    const float* convw_b = (const float*)d_in[9];
    const float* convb_b = (const float*)d_in[10];
    const float* xpw_b   = (const float*)d_in[11];
    const float* dtw_b   = (const float*)d_in[12];
    const float* dtb_b   = (const float*)d_in[13];
    const float* Alog_b  = (const float*)d_in[14];
    const float* Dv_b    = (const float*)d_in[15];
    const float* outw    = (const float*)d_in[16];
    float* out = (float*)d_out;
    float* ws  = (float*)d_ws;

    if (ws_size < WS_FLOATS * sizeof(float)) return;

    // nch=64 when the workspace extension fits; else nch=32 (legacy layout)
    const bool big = ws_size >= WS64_FLOATS * sizeof(float);
    const int  nch = big ? 64 : 32;
    const int  csh = big ? 5 : 6;             // cht = L_SEQ / nch

    float*  X    = ws + OFF_X;
    float*  ZT   = ws + OFF_ZT;
    float*  XCF  = ws + OFF_XCF;
    float*  XCB  = ws + OFF_XCB;
    float*  DLTB = ws + OFF_DLTB;
    float*  XDF  = ws + OFF_XDF;
    float*  XDB  = ws + OFF_XDB;
    float*  SS   = big ? (ws + WS_FLOATS) : (ws + OFF_SS);
    float*  HLb  = SS + (size_t)4 * nch * DI;
    __bf16* YGTF = (__bf16*)(ws + OFF_YGTF);
    __bf16* YGTB = (__bf16*)(ws + OFF_YGTB);
    float*  PF   = ws + OFF_YGTF;   // K3 split-K partials (dead until part3)
    float*  PB   = ws + OFF_YGTB;
    float*  DLTF = X;               // overwrites dead x after conv
    __bf16* IW16 = (__bf16*)(ws + OFF_SS);            // dead until scan_part1
    __bf16* HD16 = IW16 + (size_t)ETOT * DM;
    __bf16* OW16 = (__bf16*)(ws + OFF_XCB);           // dead after scan_part3
    __bf16* YGS  = (__bf16*)(ws + OFF_XCF);           // dead after scan_part3
    __bf16* XDT16F = (__bf16*)(ws + OFF_XDT16F);
    __bf16* XDT16B = (__bf16*)(ws + OFF_XDT16B);
    __bf16* DTW16F = (__bf16*)(ws + OFF_DTW16F);
    __bf16* DTW16B = (__bf16*)(ws + OFF_DTW16B);

    dim3 blk(256);
    // K0: one-time bf16 conversions (paired: inw+hid, dtw+dtw_b)
    cvt2_bf16_k<<<dim3(ETOT * DM / 2048, 2), blk, 0, stream>>>(inw, IW16, hid, HD16);
    cvt2_bf16_k<<<dim3(DI * DTR / 2048, 2), blk, 0, stream>>>(dtw, DTW16F, dtw_b, DTW16B);
    // K1: x[d][n] + zt[n][d] = in_proj_w @ hidden^T  (async bf16 MFMA, 2-phase)
    gemm_bf16<128, false, true><<<dim3(32, 32), blk, 0, stream>>>(
        IW16, HD16, X, ZT, ETOT, NTOT, DM);
    // K2: conv + silu both directions -> [n][d]
    conv_k<<<dim3(32, 64), blk, 0, stream>>>(X, convw, convb, convw_b, convb_b, XCF, XCB);
    // K3: split-K partials both branches in one launch, then fused reduce
    gemm_k3<<<dim3(32, 1, 2 * SPLK), blk, 0, stream>>>(
        xpw, XCF, PF, xpw_b, XCB, PB, RTOT, NTOT, DI);
    reduce8t_k<<<dim3(RTOT * NTOT / 1024, 2), blk, 0, stream>>>(
        PF, XDF, XDT16F, PB, XDB, XDT16B, (size_t)RTOT * NTOT);
    // K4: dlt[n][d] = softplus(dt_r^T @ dtw^T + bias)  (async bf16 MFMA)
    dtproj_mfma<<<dim3(DI / 128, NTOT / 128, 2), blk, 0, stream>>>(
        XDT16F, XDT16B, DTW16F, DTW16B, dtb, dtb_b, DLTF, DLTB);
    // K5: chunked parallel scan (runtime nch; z-gating factored out)
    scan_part1<<<dim3(DI / 256, nch, 4), blk, 0, stream>>>(
        XCF, XCB, XDF, XDB, DLTF, DLTB, Alog, Alog_b, SS, HLb, nch, csh);
    scan_part2<<<dim3(DI / 256, NST, 4), blk, 0, stream>>>(
        SS, HLb, Alog, Alog_b, nch);
    scan_part3<<<dim3(DI / 256, nch, 4), blk, 0, stream>>>(
        XCF, XCB, XDF, XDB, DLTF, DLTB, HLb, YGTF, YGTB, Alog, Alog_b, Dv, Dv_b,
        nch, csh);
    // K5b: outw -> bf16; ygsum = (ygt_f + ygt_b) * silu(zt)
    cvt_bf16_k<<<dim3(DM * DI / 2048), blk, 0, stream>>>(outw, OW16);
    gatesum_k<<<dim3(NTOT * DI / 2048), blk, 0, stream>>>(YGTF, YGTB, ZT, YGS);
    // K6: out[n][m] = out_proj_w @ ygsum  (async bf16 MFMA, MT=64, 2-phase)
    gemm_bf16<64, true, false><<<dim3(32, 16), blk, 0, stream>>>(
        OW16, YGS, out, nullptr, DM, NTOT, DI);

    (void)in_sizes; (void)n_in; (void)out_size;
}

// Round 11
// 424.475 us; speedup vs baseline: 1.0303x; 1.0303x over previous
//
#include <hip/hip_runtime.h>
#include <hip/hip_bf16.h>
#include <math.h>

// ---------------------------------------------------------------------------
// Bidirectional Mamba (bimamba v2), B=2, L=2048, D_MODEL=1024, D_INNER=2048,
// D_STATE=16, DT_RANK=64, D_CONV=4.
//
//   K0  cvt   : inw/hid + dtw/dtw_b -> bf16 (2 paired launches)
//   K1  mfma  : x[d][n] + zt[n][d] = in_proj_w @ hidden^T   (async bf16 GEMM)
//   K2  conv  : xcf/xcb[n][d] = silu(causal dwconv(x)) fp32 + bf16 copies
//   K3  mfma  : x_dbl[r][n] = xpw(bf16,128-pad) @ xc16^T — MFMA (R11;
//               replaces fp32 SIMT split-K gemm_k3 + reduce8t_k, which were
//               VALU-floor-bound: 4.3GFLOP/157TF = 27us best, measured 70us
//               w/ 5.2M LDS bank conflicts). Epilogue writes fp32 xd[r][n]
//               (r<96) AND bf16 transposed dt_r[n][r] (r<64) directly.
//   K4  mfma  : dlt[n][d] = softplus(dt_r^T @ dtw^T + bias)  (async bf16)
//   K5  scan  : 3-phase chunked scan, runtime nch (64 if ws extension fits).
//               Z-gating factored out (R10): part3 stores pre-gate y+u*D;
//               gatesum_k computes (yf+yb)*silu(z). Depth-2 u/delta register
//               pipeline + exp2 pre-scaled A rows. No launch-bounds forcing
//               (R7/R8: forcing spills, twice confirmed).
//   K5b cvt/gatesum: outw -> bf16; ygsum = (ygt_f+ygt_b)*silu(zt) (bf16)
//   K6  mfma  : out[n][m] = out_proj_w @ ygsum  (async bf16 GEMM, MT=64)
//
// gemm_bf16 / dtproj_mfma / k3_mfma: 2-phase pipeline (T3+T4): double-
// buffered LDS, counted s_waitcnt vmcnt(N) (never 0 in main loop) + raw
// s_barrier.
//
// Workspace: base 55,967,744 floats = 213.5 MiB; +8,912,896 floats
// (nch=64 SS/HL extension) = 247.5 MiB when available (R6+ confirmed).
// Region reuse: XPW16 (bf16 [2][128][2048]) lives in dead X region between
// conv and dtproj; XC16F/B (bf16 [NTOT][DI]) live in the YGTF/YGTB regions
// (dead until scan_part3).
// ---------------------------------------------------------------------------

#define L_SEQ  2048
#define B_SZ   2
#define DM     1024
#define DI     2048
#define NST    16
#define RTOT   96
#define DTR    64
#define NTOT   (B_SZ * L_SEQ)   // 4096
#define ETOT   (2 * DI)         // 4096
#define CHTMAX 64

#define LOG2E  1.44269504088896340736f

// workspace offsets (in floats)
#define OFF_X    ((size_t)0)                        // [DI][NTOT] x; XPW16; later DLTF
#define OFF_ZT   (OFF_X   + (size_t)DI * NTOT)      // [NTOT][DI] z transposed
#define OFF_XCF  (OFF_ZT  + (size_t)DI * NTOT)      // [NTOT][DI] u fwd; later ygsum (bf16)
#define OFF_XCB  (OFF_XCF + (size_t)DI * NTOT)      // [NTOT][DI] u bwd; later outw bf16
#define OFF_DLTB (OFF_XCB + (size_t)DI * NTOT)      // [NTOT][DI] delta bwd
#define OFF_XDF  (OFF_DLTB + (size_t)DI * NTOT)     // [96][NTOT]
#define OFF_XDB  (OFF_XDF + (size_t)RTOT * NTOT)
#define OFF_SS   (OFF_XDB + (size_t)RTOT * NTOT)    // [4][32][DI]; pre-K1: inw/hid bf16
#define OFF_HL   (OFF_SS  + (size_t)4 * 32 * DI)    // [4][32][NST][DI]
#define OFF_YGTF (OFF_HL  + (size_t)4 * 32 * NST * DI)    // bf16 [NTOT][DI]; XC16F
#define OFF_YGTB (OFF_YGTF + (size_t)NTOT * DI / 2)       // bf16 [NTOT][DI]; XC16B
#define OFF_XDT16F (OFF_YGTB + (size_t)NTOT * DI / 2)     // bf16 [NTOT][DTR]
#define OFF_XDT16B (OFF_XDT16F + (size_t)NTOT * DTR / 2)
#define OFF_DTW16F (OFF_XDT16B + (size_t)NTOT * DTR / 2)  // bf16 [DI][DTR]
#define OFF_DTW16B (OFF_DTW16F + (size_t)DI * DTR / 2)
#define WS_FLOATS  (OFF_DTW16B + (size_t)DI * DTR / 2)    // 55,967,744
// nch=64 extension: SS64 [4][64][DI] + HL64 [4][64][NST][DI]
#define WS64_FLOATS (WS_FLOATS + (size_t)4 * 64 * DI + (size_t)4 * 64 * NST * DI)

typedef __bf16 bf16x8 __attribute__((ext_vector_type(8)));
typedef float  floatx4 __attribute__((ext_vector_type(4)));

__device__ __forceinline__ float silu_f(float x) {
    return x / (1.f + __expf(-x));
}

// async global(16B/lane) -> LDS; dest = wave-uniform base + lane*16
__device__ __forceinline__ void gl2lds16(const __bf16* g, __bf16* l) {
    __builtin_amdgcn_global_load_lds(
        (const __attribute__((address_space(1))) unsigned int*)g,
        (__attribute__((address_space(3))) unsigned int*)l, 16, 0, 0);
}

// ---------------------------------------------------------------------------
// Async bf16 MFMA GEMM: C[M][N] (fp32) = A[M][K] @ B[N][K]^T, MT x 128 tile,
// 4 waves (2x2), BK=32. LDS rows are 32 bf16 (64 B), XOR-swizzled blocks.
// 2-phase pipeline: double-buffered LDS, counted vmcnt, raw barriers.
// TRANS: C stored [N][M]. SPLITZ: gm<DI -> C[d][n]; gm>=DI -> C2[n][gm-DI].
// ---------------------------------------------------------------------------
template<int MT, bool TRANS, bool SPLITZ>
__global__ __launch_bounds__(256)
void gemm_bf16(const __bf16* __restrict__ A, const __bf16* __restrict__ B,
               float* __restrict__ C, float* __restrict__ C2,
               int M, int N, int K)
{
    static_assert(MT == 64 || MT == 128, "vmcnt literals assume MT in {64,128}");
    __shared__ __attribute__((aligned(16))) __bf16 As[2][MT * 32];
    __shared__ __attribute__((aligned(16))) __bf16 Bs[2][128 * 32];
    const int tid  = threadIdx.x;
    const int m0   = blockIdx.y * MT;
    const int n0   = blockIdx.x * 128;
    const int lane = tid & 63;
    const int wave = tid >> 6;
    const int wy   = wave >> 1, wx = wave & 1;
    const int lr   = lane & 15;
    const int q    = lane >> 4;
    constexpr int MF = MT / 32;

    floatx4 acc[MF][4];
#pragma unroll
    for (int i = 0; i < MF; ++i)
#pragma unroll
        for (int j = 0; j < 4; ++j) acc[i][j] = (floatx4)(0.0f);

    const int rl = lane >> 2;
    const int cp = lane & 3;
    const int sw = (q ^ ((lr >> 2) & 3)) * 8;

    auto stage = [&](int s, int k0) {
#pragma unroll
        for (int is = 0; is < MT / 64; ++is) {
            int r0  = wave * (MT / 4) + is * 16;
            int row = r0 + rl;
            int c   = cp ^ ((row >> 2) & 3);
            gl2lds16(A + (size_t)(m0 + row) * K + k0 + c * 8, &As[s][r0 * 32]);
        }
#pragma unroll
        for (int is = 0; is < 2; ++is) {
            int r0  = wave * 32 + is * 16;
            int row = r0 + rl;
            int c   = cp ^ ((row >> 2) & 3);
            gl2lds16(B + (size_t)(n0 + row) * K + k0 + c * 8, &Bs[s][r0 * 32]);
        }
    };

    stage(0, 0);                     // prologue: tile 0 in flight
    int cur = 0;
    for (int k0 = 0; k0 < K; k0 += 32) {
        if (k0 + 32 < K) {
            stage(cur ^ 1, k0 + 32); // issue next tile BEFORE computing current
            if constexpr (MT == 128) {
                asm volatile("s_waitcnt vmcnt(4)" ::: "memory");  // cur tile landed
            } else {
                asm volatile("s_waitcnt vmcnt(3)" ::: "memory");
            }
        } else {
            asm volatile("s_waitcnt vmcnt(0)" ::: "memory");      // last tile
        }
        __builtin_amdgcn_s_barrier();   // all waves' cur-tile DMA visible

        bf16x8 af[MF], bfr[4];
#pragma unroll
        for (int i = 0; i < MF; ++i)
            af[i] = *(const bf16x8*)&As[cur][(wy * (MT / 2) + i * 16 + lr) * 32 + sw];
#pragma unroll
        for (int j = 0; j < 4; ++j)
            bfr[j] = *(const bf16x8*)&Bs[cur][(wx * 64 + j * 16 + lr) * 32 + sw];
#pragma unroll
        for (int i = 0; i < MF; ++i)
#pragma unroll
            for (int j = 0; j < 4; ++j)
                acc[i][j] = __builtin_amdgcn_mfma_f32_16x16x32_bf16(
                    af[i], bfr[j], acc[i][j], 0, 0, 0);
        __builtin_amdgcn_s_barrier();   // reads of buf[cur] done -> next iter
        cur ^= 1;                       // may overwrite it
    }

    const int mb = m0 + wy * (MT / 2);
    const int nb = n0 + wx * 64;
#pragma unroll
    for (int i = 0; i < MF; ++i) {
#pragma unroll
        for (int j = 0; j < 4; ++j) {
            int gn  = nb + j * 16 + lr;
            int gm0 = mb + i * 16 + q * 4;     // rows gm0..gm0+3 <- acc[i][j][0..3]
            if constexpr (SPLITZ) {
                if (m0 < DI) {
#pragma unroll
                    for (int r = 0; r < 4; ++r)
                        C[(size_t)(gm0 + r) * N + gn] = acc[i][j][r];
                } else {
                    *(floatx4*)&C2[(size_t)gn * DI + (gm0 - DI)] = acc[i][j];
                }
            } else if constexpr (TRANS) {
                *(floatx4*)&C[(size_t)gn * M + gm0] = acc[i][j];
            } else {
#pragma unroll
                for (int r = 0; r < 4; ++r)
                    C[(size_t)(gm0 + r) * N + gn] = acc[i][j][r];
            }
        }
    }
}

// ---------------------------------------------------------------------------
// K3 (R11): x_dbl = xpw(128-pad bf16) @ xc16^T via MFMA, both branches via
// blockIdx.z. M=128 (one tile), N=NTOT, K=DI. Epilogue: fp32 C[r][n] for
// r<RTOT and bf16 T[n][r] (transposed dt_r) for r<DTR.
// ---------------------------------------------------------------------------
__global__ __launch_bounds__(256)
void k3_mfma(const __bf16* __restrict__ Af, const __bf16* __restrict__ Ab,
             const __bf16* __restrict__ Bf, const __bf16* __restrict__ Bb,
             float* __restrict__ Cf, float* __restrict__ Cb,
             __bf16* __restrict__ Tf, __bf16* __restrict__ Tb)
{
    __shared__ __attribute__((aligned(16))) __bf16 As[2][128 * 32];
    __shared__ __attribute__((aligned(16))) __bf16 Bs[2][128 * 32];
    const int br = blockIdx.z;
    const __bf16* A = br ? Ab : Af;     // [128][DI]
    const __bf16* B = br ? Bb : Bf;     // [NTOT][DI]
    float*        C = br ? Cb : Cf;     // [RTOT][NTOT]
    __bf16*       T = br ? Tb : Tf;     // [NTOT][DTR]

    const int tid  = threadIdx.x;
    const int n0   = blockIdx.x * 128;
    const int lane = tid & 63;
    const int wave = tid >> 6;
    const int wy   = wave >> 1, wx = wave & 1;
    const int lr   = lane & 15;
    const int q    = lane >> 4;

    floatx4 acc[4][4];
#pragma unroll
    for (int i = 0; i < 4; ++i)
#pragma unroll
        for (int j = 0; j < 4; ++j) acc[i][j] = (floatx4)(0.0f);

    const int rl = lane >> 2;
    const int cp = lane & 3;
    const int sw = (q ^ ((lr >> 2) & 3)) * 8;

    auto stage = [&](int s, int k0) {
#pragma unroll
        for (int is = 0; is < 2; ++is) {
            int r0  = wave * 32 + is * 16;
            int row = r0 + rl;
            int c   = cp ^ ((row >> 2) & 3);
            gl2lds16(A + (size_t)row * DI + k0 + c * 8, &As[s][r0 * 32]);
        }
#pragma unroll
        for (int is = 0; is < 2; ++is) {
            int r0  = wave * 32 + is * 16;
            int row = r0 + rl;
            int c   = cp ^ ((row >> 2) & 3);
            gl2lds16(B + (size_t)(n0 + row) * DI + k0 + c * 8, &Bs[s][r0 * 32]);
        }
    };

    stage(0, 0);
    int cur = 0;
    for (int k0 = 0; k0 < DI; k0 += 32) {
        if (k0 + 32 < DI) {
            stage(cur ^ 1, k0 + 32);
            asm volatile("s_waitcnt vmcnt(4)" ::: "memory");
        } else {
            asm volatile("s_waitcnt vmcnt(0)" ::: "memory");
        }
        __builtin_amdgcn_s_barrier();

        bf16x8 af[4], bfr[4];
#pragma unroll
        for (int i = 0; i < 4; ++i)
            af[i] = *(const bf16x8*)&As[cur][(wy * 64 + i * 16 + lr) * 32 + sw];
#pragma unroll
        for (int j = 0; j < 4; ++j)
            bfr[j] = *(const bf16x8*)&Bs[cur][(wx * 64 + j * 16 + lr) * 32 + sw];
#pragma unroll
        for (int i = 0; i < 4; ++i)
#pragma unroll
            for (int j = 0; j < 4; ++j)
                acc[i][j] = __builtin_amdgcn_mfma_f32_16x16x32_bf16(
                    af[i], bfr[j], acc[i][j], 0, 0, 0);
        __builtin_amdgcn_s_barrier();
        cur ^= 1;
    }

    const int mb = wy * 64;
    const int nb = n0 + wx * 64;
#pragma unroll
    for (int i = 0; i < 4; ++i) {
#pragma unroll
        for (int j = 0; j < 4; ++j) {
            int gn  = nb + j * 16 + lr;
#pragma unroll
            for (int r = 0; r < 4; ++r) {
                int gm = mb + i * 16 + q * 4 + r;
                float val = acc[i][j][r];
                if (gm < RTOT) C[(size_t)gm * NTOT + gn] = val;
                if (gm < DTR)  T[(size_t)gn * DTR + gm] = (__bf16)val;
            }
        }
    }
}

// ---------------------------------------------------------------------------
// K4: dlt[n][d] = softplus(dt_r^T[n][r] @ dtw[d][r]^T + bias[d]).
// Async bf16 MFMA, M=NTOT, N=DI, K=DTR=64 (2 tiles, both issued up front),
// 128x128 tile, both branches via blockIdx.z. Coalesced [n][d] stores.
// ---------------------------------------------------------------------------
__global__ __launch_bounds__(256)
void dtproj_mfma(const __bf16* __restrict__ Af, const __bf16* __restrict__ Ab,
                 const __bf16* __restrict__ Bwf, const __bf16* __restrict__ Bwb,
                 const float* __restrict__ bif, const float* __restrict__ bib,
                 float* __restrict__ outf, float* __restrict__ outb)
{
    __shared__ __attribute__((aligned(16))) __bf16 As[2][128 * 32];
    __shared__ __attribute__((aligned(16))) __bf16 Bs[2][128 * 32];
    const int br = blockIdx.z;
    const __bf16* A  = br ? Ab : Af;     // [NTOT][DTR]
    const __bf16* B  = br ? Bwb : Bwf;   // [DI][DTR]
    const float*  bi = br ? bib : bif;
    float*        C  = br ? outb : outf; // [NTOT][DI]

    const int tid  = threadIdx.x;
    const int m0   = blockIdx.y * 128;   // n dim
    const int n0   = blockIdx.x * 128;   // d dim
    const int lane = tid & 63;
    const int wave = tid >> 6;
    const int wy   = wave >> 1, wx = wave & 1;
    const int lr   = lane & 15;
    const int q    = lane >> 4;

    floatx4 acc[4][4];
#pragma unroll
    for (int i = 0; i < 4; ++i)
#pragma unroll
        for (int j = 0; j < 4; ++j) acc[i][j] = (floatx4)(0.0f);

    const int rl = lane >> 2;
    const int cp = lane & 3;
    const int sw = (q ^ ((lr >> 2) & 3)) * 8;

    // issue both k-tiles (per wave: 2x(A+B) = 4 loads per tile, 8 total)
#pragma unroll
    for (int t = 0; t < 2; ++t) {
        int k0 = t * 32;
#pragma unroll
        for (int is = 0; is < 2; ++is) {
            int r0  = wave * 32 + is * 16;
            int row = r0 + rl;
            int c   = cp ^ ((row >> 2) & 3);
            gl2lds16(A + (size_t)(m0 + row) * DTR + k0 + c * 8, &As[t][r0 * 32]);
            gl2lds16(B + (size_t)(n0 + row) * DTR + k0 + c * 8, &Bs[t][r0 * 32]);
        }
    }

#pragma unroll
    for (int t = 0; t < 2; ++t) {
        if (t == 0) asm volatile("s_waitcnt vmcnt(4)" ::: "memory");
        else        asm volatile("s_waitcnt vmcnt(0)" ::: "memory");
        __builtin_amdgcn_s_barrier();

        bf16x8 af[4], bfr[4];
#pragma unroll
        for (int i = 0; i < 4; ++i)
            af[i] = *(const bf16x8*)&As[t][(wy * 64 + i * 16 + lr) * 32 + sw];
#pragma unroll
        for (int j = 0; j < 4; ++j)
            bfr[j] = *(const bf16x8*)&Bs[t][(wx * 64 + j * 16 + lr) * 32 + sw];
#pragma unroll
        for (int i = 0; i < 4; ++i)
#pragma unroll
            for (int j = 0; j < 4; ++j)
                acc[i][j] = __builtin_amdgcn_mfma_f32_16x16x32_bf16(
                    af[i], bfr[j], acc[i][j], 0, 0, 0);
    }

    const int mb = m0 + wy * 64;
    const int nb = n0 + wx * 64;
    float bj[4];
#pragma unroll
    for (int j = 0; j < 4; ++j) bj[j] = bi[nb + j * 16 + lr];
#pragma unroll
    for (int i = 0; i < 4; ++i) {
#pragma unroll
        for (int r = 0; r < 4; ++r) {
            int gm = mb + i * 16 + q * 4 + r;
#pragma unroll
            for (int j = 0; j < 4; ++j) {
                int gn = nb + j * 16 + lr;
                float x = acc[i][j][r] + bj[j];
                float o = (x > 20.f) ? x : __logf(1.f + __expf(x));
                C[(size_t)gm * DI + gn] = o;
            }
        }
    }
}

// ---------------------------------------------------------------------------
// cvt fp32 -> bf16, 8 elems/thread; paired launch (blockIdx.y selects set).
// ---------------------------------------------------------------------------
__global__ __launch_bounds__(256)
void cvt2_bf16_k(const float* __restrict__ ia, __bf16* __restrict__ oa,
                 const float* __restrict__ ib, __bf16* __restrict__ ob)
{
    const float* in  = blockIdx.y ? ib : ia;
    __bf16*      out = blockIdx.y ? ob : oa;
    const size_t i = ((size_t)blockIdx.x * 256 + threadIdx.x) * 8;
    float4 a = *(const float4*)(in + i);
    float4 b = *(const float4*)(in + i + 4);
    bf16x8 p;
    p[0]=(__bf16)a.x; p[1]=(__bf16)a.y; p[2]=(__bf16)a.z; p[3]=(__bf16)a.w;
    p[4]=(__bf16)b.x; p[5]=(__bf16)b.y; p[6]=(__bf16)b.z; p[7]=(__bf16)b.w;
    *(bf16x8*)(out + i) = p;
}

__global__ __launch_bounds__(256)
void cvt_bf16_k(const float* __restrict__ in, __bf16* __restrict__ out)
{
    const size_t i = ((size_t)blockIdx.x * 256 + threadIdx.x) * 8;
    float4 a = *(const float4*)(in + i);
    float4 b = *(const float4*)(in + i + 4);
    bf16x8 p;
    p[0]=(__bf16)a.x; p[1]=(__bf16)a.y; p[2]=(__bf16)a.z; p[3]=(__bf16)a.w;
    p[4]=(__bf16)b.x; p[5]=(__bf16)b.y; p[6]=(__bf16)b.z; p[7]=(__bf16)b.w;
    *(bf16x8*)(out + i) = p;
}

// ---------------------------------------------------------------------------
// cvt_pad_xpw: xpw [RTOT][DI] fp32 -> [128][DI] bf16 zero-padded rows.
// blockIdx.y selects branch.
// ---------------------------------------------------------------------------
__global__ __launch_bounds__(256)
void cvt_pad_xpw(const float* __restrict__ xf, const float* __restrict__ xb,
                 __bf16* __restrict__ of, __bf16* __restrict__ ob)
{
    const float* in  = blockIdx.y ? xb : xf;
    __bf16*      out = blockIdx.y ? ob : of;
    const size_t i = ((size_t)blockIdx.x * 256 + threadIdx.x) * 8;   // over 128*DI
    const int r = (int)(i / DI);
    bf16x8 p;
    if (r < RTOT) {
        float4 a = *(const float4*)(in + i);
        float4 b = *(const float4*)(in + i + 4);
        p[0]=(__bf16)a.x; p[1]=(__bf16)a.y; p[2]=(__bf16)a.z; p[3]=(__bf16)a.w;
        p[4]=(__bf16)b.x; p[5]=(__bf16)b.y; p[6]=(__bf16)b.z; p[7]=(__bf16)b.w;
    } else {
#pragma unroll
        for (int e = 0; e < 8; ++e) p[e] = (__bf16)0.f;
    }
    *(bf16x8*)(out + i) = p;
}

// ---------------------------------------------------------------------------
// gatesum_k: o[i] = bf16( ((float)a[i] + (float)b[i]) * silu(z[i]) ).
// ---------------------------------------------------------------------------
__global__ __launch_bounds__(256)
void gatesum_k(const __bf16* __restrict__ a, const __bf16* __restrict__ b,
               const float* __restrict__ z, __bf16* __restrict__ o)
{
    const size_t i = ((size_t)blockIdx.x * 256 + threadIdx.x) * 8;
    bf16x8 x = *(const bf16x8*)(a + i);
    bf16x8 y = *(const bf16x8*)(b + i);
    float4 z0 = *(const float4*)(z + i);
    float4 z1 = *(const float4*)(z + i + 4);
    float zz[8] = { z0.x, z0.y, z0.z, z0.w, z1.x, z1.y, z1.z, z1.w };
    bf16x8 s;
#pragma unroll
    for (int e = 0; e < 8; ++e)
        s[e] = (__bf16)(((float)x[e] + (float)y[e]) * silu_f(zz[e]));
    *(bf16x8*)(o + i) = s;
}

// ---------------------------------------------------------------------------
// Causal depthwise conv (K=4) + silu, both directions; x [d][n] -> [n][d]
// fp32 xcf/xcb (scan u-operand) + bf16 xc16f/xc16b (K3 MFMA B-operand).
// ---------------------------------------------------------------------------
__global__ __launch_bounds__(256)
void conv_k(const float* __restrict__ x,
            const float* __restrict__ wf, const float* __restrict__ bf,
            const float* __restrict__ wb, const float* __restrict__ bb,
            float* __restrict__ xcf, float* __restrict__ xcb,
            __bf16* __restrict__ xc16f, __bf16* __restrict__ xc16b)
{
    __shared__ float xs[70 * 65];
    const int tid = threadIdx.x;
    const int d0 = blockIdx.x * 64;
    const int n0 = blockIdx.y * 64;
    const int b  = n0 >> 11;
    const int l0 = n0 & (L_SEQ - 1);
    const size_t bbase = (size_t)b << 11;

    for (int i = tid; i < 64 * 70; i += 256) {
        int r = i / 70, c = i % 70;
        int l = l0 - 3 + c;
        float v = 0.f;
        if (l >= 0 && l < L_SEQ) v = x[(size_t)(d0 + r) * NTOT + bbase + l];
        xs[c * 65 + r] = v;
    }
    __syncthreads();

    const int dd = tid & 63;
    const int lq = tid >> 6;
    const int d  = d0 + dd;
    const float w0 = wf[d * 4 + 0], w1 = wf[d * 4 + 1];
    const float w2 = wf[d * 4 + 2], w3 = wf[d * 4 + 3];
    const float v0 = wb[d * 4 + 0], v1 = wb[d * 4 + 1];
    const float v2 = wb[d * 4 + 2], v3 = wb[d * 4 + 3];
    const float bfv = bf[d], bbv = bb[d];

    for (int lr = 0; lr < 64; lr += 4) {
        const int lo = lr + lq;
        const int l  = l0 + lo;
        float x0 = xs[(lo + 0) * 65 + dd];
        float x1 = xs[(lo + 1) * 65 + dd];
        float x2 = xs[(lo + 2) * 65 + dd];
        float x3 = xs[(lo + 3) * 65 + dd];
        float x4 = xs[(lo + 4) * 65 + dd];
        float x5 = xs[(lo + 5) * 65 + dd];
        float x6 = xs[(lo + 6) * 65 + dd];
        float xf = bfv + w0 * x0 + w1 * x1 + w2 * x2 + w3 * x3;
        float sf = silu_f(xf);
        size_t nf = (size_t)bbase + l;
        xcf[nf * DI + d]   = sf;
        xc16f[nf * DI + d] = (__bf16)sf;
        float xb = bbv + v3 * x3 + v2 * x4 + v1 * x5 + v0 * x6;
        float sb = silu_f(xb);
        size_t nb2 = (size_t)bbase + (L_SEQ - 1 - l);
        xcb[nb2 * DI + d]   = sb;
        xc16b[nb2 * DI + d] = (__bf16)sb;
    }
}

// ---------------------------------------------------------------------------
// Chunked scan phase 1 (runtime nch). B rows staged in LDS (broadcast);
// u/delta DEPTH-2 register pipeline; exp2 pre-scaled A rows. No forcing.
// ---------------------------------------------------------------------------
__global__ __launch_bounds__(256)
void scan_part1(const float* __restrict__ xcf, const float* __restrict__ xcb,
                const float* __restrict__ xdf, const float* __restrict__ xdb,
                const float* __restrict__ dltf, const float* __restrict__ dltb,
                const float* __restrict__ Alog_f, const float* __restrict__ Alog_b,
                float* __restrict__ SS, float* __restrict__ HL,
                int nch, int csh)
{
    __shared__ float Bsh[NST][CHTMAX];
    const int cht = 1 << csh;
    const int tid = threadIdx.x;
    const int d  = blockIdx.x * 256 + tid;
    const int c  = blockIdx.y;
    const int bb = blockIdx.z;
    const int b  = bb & 1;
    const int br = bb >> 1;

    const float* u    = br ? xcb : xcf;
    const float* dl   = br ? dltb : dltf;
    const float* xd   = br ? xdb : xdf;
    const float* Alog = br ? Alog_b : Alog_f;

    const size_t nbase = (size_t)b * L_SEQ + (size_t)c * cht;
    const float* bcB = xd + (size_t)DTR * NTOT + nbase;

    // stage B[n][t] into LDS, coalesced over t
    for (int i = tid; i < NST * cht; i += 256) {
        int n = i >> csh;
        int t = i & (cht - 1);
        Bsh[n][t] = bcB[(size_t)n * NTOT + t];
    }

    float Arow[NST], h[NST];
#pragma unroll
    for (int n = 0; n < NST; ++n) {
        Arow[n] = -__expf(Alog[d * NST + n]) * LOG2E;   // pre-scaled for exp2
        h[n] = 0.f;
    }
    float S = 0.f;

    const float* up = u  + nbase * DI + d;
    const float* dp = dl + nbase * DI + d;

    __syncthreads();

    // depth-2 pipeline: preload groups 0 and 1
    float dva[4], uva[4], dvb[4], uvb[4];
#pragma unroll
    for (int k = 0; k < 4; ++k) {
        dva[k] = dp[(size_t)k * DI];
        uva[k] = up[(size_t)k * DI];
    }
#pragma unroll
    for (int k = 0; k < 4; ++k) {
        dvb[k] = dp[(size_t)(4 + k) * DI];
        uvb[k] = up[(size_t)(4 + k) * DI];
    }

    for (int tr = 0; tr < cht; tr += 4) {
        // prefetch group tr+8 (over-reads land in adjacent live workspace
        // regions — in-bounds, values unused)
        float dvn[4], uvn[4];
#pragma unroll
        for (int k = 0; k < 4; ++k) {
            dvn[k] = dp[(size_t)(tr + 8 + k) * DI];
            uvn[k] = up[(size_t)(tr + 8 + k) * DI];
        }
        S += (dva[0] + dva[1]) + (dva[2] + dva[3]);
        float du[4] = { dva[0]*uva[0], dva[1]*uva[1], dva[2]*uva[2], dva[3]*uva[3] };
#pragma unroll
        for (int n = 0; n < NST; ++n) {
            float4 Bn = *(const float4*)&Bsh[n][tr];
            float hn = h[n];
            float An = Arow[n];
            hn = hn * __builtin_amdgcn_exp2f(dva[0] * An) + du[0] * Bn.x;
            hn = hn * __builtin_amdgcn_exp2f(dva[1] * An) + du[1] * Bn.y;
            hn = hn * __builtin_amdgcn_exp2f(dva[2] * An) + du[2] * Bn.z;
            hn = hn * __builtin_amdgcn_exp2f(dva[3] * An) + du[3] * Bn.w;
            h[n] = hn;
        }
#pragma unroll
        for (int k = 0; k < 4; ++k) {
            dva[k] = dvb[k]; uva[k] = uvb[k];
            dvb[k] = dvn[k]; uvb[k] = uvn[k];
        }
    }
    SS[((size_t)bb * nch + c) * DI + d] = S;
#pragma unroll
    for (int n = 0; n < NST; ++n)
        HL[(((size_t)bb * nch + c) * NST + n) * DI + d] = h[n];
}

__global__ __launch_bounds__(256)
void scan_part2(const float* __restrict__ SS, float* HL,
                const float* __restrict__ Alog_f, const float* __restrict__ Alog_b,
                int nch)
{
    const int d  = blockIdx.x * 256 + threadIdx.x;
    const int n  = blockIdx.y;
    const int bb = blockIdx.z;
    const int br = bb >> 1;
    const float* Alog = br ? Alog_b : Alog_f;
    const float A = -__expf(Alog[d * NST + n]) * LOG2E;

    float H = 0.f;
    for (int c = 0; c < nch; ++c) {
        const size_t si = ((size_t)bb * nch + c) * DI + d;
        const size_t hi = (((size_t)bb * nch + c) * NST + n) * DI + d;
        float hl = HL[hi];
        HL[hi] = H;
        H = __builtin_amdgcn_exp2f(SS[si] * A) * H + hl;
    }
}

// ---------------------------------------------------------------------------
// Chunked scan phase 3 (runtime nch). Z-gating removed (done in gatesum_k):
// stores pre-gate bf16(y + u*D). B/C staged in LDS; u/delta DEPTH-2
// register pipeline; exp2 pre-scaled A rows.
// ---------------------------------------------------------------------------
__global__ __launch_bounds__(256)
void scan_part3(const float* __restrict__ xcf, const float* __restrict__ xcb,
                const float* __restrict__ xdf, const float* __restrict__ xdb,
                const float* __restrict__ dltf, const float* __restrict__ dltb,
                const float* __restrict__ HIN,
                __bf16* __restrict__ ygtf, __bf16* __restrict__ ygtb,
                const float* __restrict__ Alog_f, const float* __restrict__ Alog_b,
                const float* __restrict__ Df, const float* __restrict__ Db,
                int nch, int csh)
{
    __shared__ float BCs[2 * NST][CHTMAX];   // rows 0..15 = B, 16..31 = C
    const int cht = 1 << csh;
    const int tid = threadIdx.x;
    const int d  = blockIdx.x * 256 + tid;
    const int c  = blockIdx.y;
    const int bb = blockIdx.z;
    const int b  = bb & 1;
    const int br = bb >> 1;

    const float* u    = br ? xcb : xcf;
    const float* dl   = br ? dltb : dltf;
    const float* xd   = br ? xdb : xdf;
    const float* Alog = br ? Alog_b : Alog_f;
    const float* Dv   = br ? Db : Df;
    __bf16*      ygt  = br ? ygtb : ygtf;

    const size_t nbase = (size_t)b * L_SEQ + (size_t)c * cht;
    const float* bcB = xd + (size_t)DTR * NTOT + nbase;

    // stage B and C; rows DTR.. are contiguous in xd
    for (int i = tid; i < 2 * NST * cht; i += 256) {
        int n = i >> csh;
        int t = i & (cht - 1);
        BCs[n][t] = bcB[(size_t)n * NTOT + t];
    }

    float Arow[NST], h[NST];
#pragma unroll
    for (int n = 0; n < NST; ++n) {
        Arow[n] = -__expf(Alog[d * NST + n]) * LOG2E;   // pre-scaled for exp2
        h[n] = HIN[(((size_t)bb * nch + c) * NST + n) * DI + d];
    }
    const float Dp = Dv[d];

    const float* up = u  + nbase * DI + d;
    const float* dp = dl + nbase * DI + d;
    const int    bL = b * L_SEQ;
    const int    t0 = c * cht;

    __syncthreads();

    // depth-2 pipeline for u/delta
    float dva[4], uva[4], dvb[4], uvb[4];
#pragma unroll
    for (int k = 0; k < 4; ++k) {
        dva[k] = dp[(size_t)k * DI];
        uva[k] = up[(size_t)k * DI];
    }
#pragma unroll
    for (int k = 0; k < 4; ++k) {
        dvb[k] = dp[(size_t)(4 + k) * DI];
        uvb[k] = up[(size_t)(4 + k) * DI];
    }

    for (int tr = 0; tr < cht; tr += 4) {
        // prefetch u/delta group tr+8 (over-reads land in adjacent live
        // workspace regions — in-bounds, values unused)
        float dvn[4], uvn[4];
#pragma unroll
        for (int k = 0; k < 4; ++k) {
            dvn[k] = dp[(size_t)(tr + 8 + k) * DI];
            uvn[k] = up[(size_t)(tr + 8 + k) * DI];
        }

        float du[4] = { dva[0]*uva[0], dva[1]*uva[1], dva[2]*uva[2], dva[3]*uva[3] };
        float y[4] = { 0.f, 0.f, 0.f, 0.f };
#pragma unroll
        for (int n = 0; n < NST; ++n) {
            float4 Bn = *(const float4*)&BCs[n][tr];
            float4 Cn = *(const float4*)&BCs[NST + n][tr];
            float hn = h[n];
            float An = Arow[n];
            hn = hn * __builtin_amdgcn_exp2f(dva[0] * An) + du[0] * Bn.x;  y[0] = fmaf(hn, Cn.x, y[0]);
            hn = hn * __builtin_amdgcn_exp2f(dva[1] * An) + du[1] * Bn.y;  y[1] = fmaf(hn, Cn.y, y[1]);
            hn = hn * __builtin_amdgcn_exp2f(dva[2] * An) + du[2] * Bn.z;  y[2] = fmaf(hn, Cn.z, y[2]);
            hn = hn * __builtin_amdgcn_exp2f(dva[3] * An) + du[3] * Bn.w;  y[3] = fmaf(hn, Cn.w, y[3]);
            h[n] = hn;
        }
#pragma unroll
        for (int k = 0; k < 4; ++k) {
            int t = t0 + tr + k;
            int nn = br ? (bL + (L_SEQ - 1 - t)) : (bL + t);
            ygt[(size_t)nn * DI + d] = (__bf16)(y[k] + uva[k] * Dp);
        }
#pragma unroll
        for (int k = 0; k < 4; ++k) {
            dva[k] = dvb[k]; uva[k] = uvb[k];
            dvb[k] = dvn[k]; uvb[k] = uvn[k];
        }
    }
}

extern "C" void kernel_launch(void* const* d_in, const int* in_sizes, int n_in,
                              void* d_out, int out_size, void* d_ws, size_t ws_size,
                              hipStream_t stream)
{
    const float* hid     = (const float*)d_in[0];
    const float* inw     = (const float*)d_in[1];
    const float* convw   = (const float*)d_in[2];
    const float* convb   = (const float*)d_in[3];
    const float* xpw     = (const float*)d_in[4];
    const float* dtw     = (const float*)d_in[5];
    const float* dtb     = (const float*)d_in[6];
    const float* Alog    = (const float*)d_in[7];
    const float* Dv      = (const float*)d_in[8];
    const float* convw_b = (const float*)d_in[9];
    const float* convb_b = (const float*)d_in[10];
    const float* xpw_b   = (const float*)d_in[11];
    const float* dtw_b   = (const float*)d_in[12];
    const float* dtb_b   = (const float*)d_in[13];
    const float* Alog_b  = (const float*)d_in[14];
    const float* Dv_b    = (const float*)d_in[15];
    const float* outw    = (const float*)d_in[16];
    float* out = (float*)d_out;
    float* ws  = (float*)d_ws;

    if (ws_size < WS_FLOATS * sizeof(float)) return;

    // nch=64 when the workspace extension fits; else nch=32 (legacy layout)
    const bool big = ws_size >= WS64_FLOATS * sizeof(float);
    const int  nch = big ? 64 : 32;
    const int  csh = big ? 5 : 6;             // cht = L_SEQ / nch

    float*  X    = ws + OFF_X;
    float*  ZT   = ws + OFF_ZT;
    float*  XCF  = ws + OFF_XCF;
    float*  XCB  = ws + OFF_XCB;
    float*  DLTB = ws + OFF_DLTB;
    float*  XDF  = ws + OFF_XDF;
    float*  XDB  = ws + OFF_XDB;
    float*  SS   = big ? (ws + WS_FLOATS) : (ws + OFF_SS);
    float*  HLb  = SS + (size_t)4 * nch * DI;
    __bf16* YGTF = (__bf16*)(ws + OFF_YGTF);
    __bf16* YGTB = (__bf16*)(ws + OFF_YGTB);
    __bf16* XC16F = (__bf16*)(ws + OFF_YGTF);         // dead until scan_part3
    __bf16* XC16B = (__bf16*)(ws + OFF_YGTB);
    float*  DLTF = X;               // overwrites dead x after K3
    __bf16* XPW16F = (__bf16*)(ws + OFF_X);           // dead x region, post-conv
    __bf16* XPW16B = XPW16F + (size_t)128 * DI;
    __bf16* IW16 = (__bf16*)(ws + OFF_SS);            // dead until scan_part1
    __bf16* HD16 = IW16 + (size_t)ETOT * DM;
    __bf16* OW16 = (__bf16*)(ws + OFF_XCB);           // dead after scan_part3
    __bf16* YGS  = (__bf16*)(ws + OFF_XCF);           // dead after scan_part3
    __bf16* XDT16F = (__bf16*)(ws + OFF_XDT16F);
    __bf16* XDT16B = (__bf16*)(ws + OFF_XDT16B);
    __bf16* DTW16F = (__bf16*)(ws + OFF_DTW16F);
    __bf16* DTW16B = (__bf16*)(ws + OFF_DTW16B);

    dim3 blk(256);
    // K0: one-time bf16 conversions (paired: inw+hid, dtw+dtw_b)
    cvt2_bf16_k<<<dim3(ETOT * DM / 2048, 2), blk, 0, stream>>>(inw, IW16, hid, HD16);
    cvt2_bf16_k<<<dim3(DI * DTR / 2048, 2), blk, 0, stream>>>(dtw, DTW16F, dtw_b, DTW16B);
    // K1: x[d][n] + zt[n][d] = in_proj_w @ hidden^T  (async bf16 MFMA, 2-phase)
    gemm_bf16<128, false, true><<<dim3(32, 32), blk, 0, stream>>>(
        IW16, HD16, X, ZT, ETOT, NTOT, DM);
    // K2: conv + silu both directions -> fp32 [n][d] + bf16 copies
    conv_k<<<dim3(32, 64), blk, 0, stream>>>(
        X, convw, convb, convw_b, convb_b, XCF, XCB, XC16F, XC16B);
    // K3: xpw -> padded bf16 (into now-dead X region), then MFMA GEMM
    // writing fp32 xd[r][n] + bf16 transposed dt_r[n][r]
    cvt_pad_xpw<<<dim3(128 * DI / 2048, 2), blk, 0, stream>>>(
        xpw, xpw_b, XPW16F, XPW16B);
    k3_mfma<<<dim3(32, 1, 2), blk, 0, stream>>>(
        XPW16F, XPW16B, XC16F, XC16B, XDF, XDB, XDT16F, XDT16B);
    // K4: dlt[n][d] = softplus(dt_r^T @ dtw^T + bias)  (async bf16 MFMA)
    // (writes DLTF over the X region — XPW16 is dead by now)
    dtproj_mfma<<<dim3(DI / 128, NTOT / 128, 2), blk, 0, stream>>>(
        XDT16F, XDT16B, DTW16F, DTW16B, dtb, dtb_b, DLTF, DLTB);
    // K5: chunked parallel scan (runtime nch; z-gating factored out)
    scan_part1<<<dim3(DI / 256, nch, 4), blk, 0, stream>>>(
        XCF, XCB, XDF, XDB, DLTF, DLTB, Alog, Alog_b, SS, HLb, nch, csh);
    scan_part2<<<dim3(DI / 256, NST, 4), blk, 0, stream>>>(
        SS, HLb, Alog, Alog_b, nch);
    scan_part3<<<dim3(DI / 256, nch, 4), blk, 0, stream>>>(
        XCF, XCB, XDF, XDB, DLTF, DLTB, HLb, YGTF, YGTB, Alog, Alog_b, Dv, Dv_b,
        nch, csh);
    // K5b: outw -> bf16; ygsum = (ygt_f + ygt_b) * silu(zt)
    cvt_bf16_k<<<dim3(DM * DI / 2048), blk, 0, stream>>>(outw, OW16);
    gatesum_k<<<dim3(NTOT * DI / 2048), blk, 0, stream>>>(YGTF, YGTB, ZT, YGS);
    // K6: out[n][m] = out_proj_w @ ygsum  (async bf16 MFMA, MT=64, 2-phase)
    gemm_bf16<64, true, false><<<dim3(32, 16), blk, 0, stream>>>(
        OW16, YGS, out, nullptr, DM, NTOT, DI);

    (void)in_sizes; (void)n_in; (void)out_size;
}